// Round 1
// baseline (23955.794 us; speedup 1.0000x reference)
//
#include <hip/hip_runtime.h>
#include <stdint.h>

#define AGENT __HIP_MEMORY_SCOPE_AGENT

// x[64][256][256] -> xT[t][iq][b][4]   (packed quads of input dim, batch-minor)
__global__ __launch_bounds__(256) void xpose_in(const float* __restrict__ x,
                                                float* __restrict__ xT) {
  const int t = blockIdx.x;
  const int b = threadIdx.x & 63;
  const int w = threadIdx.x >> 6;
  const float* xr = x + ((size_t)b * 256 + t) * 256;
  float* o = xT + (size_t)t * 64 * 256;
  for (int iq = w * 16; iq < w * 16 + 16; ++iq) {
    float4 v = *(const float4*)(xr + iq * 4);
    *(float4*)(o + ((size_t)iq * 64 + b) * 4) = v;
  }
}

// Pack [W;U] ([KT][4H], col cg) into wuT[cg][k] (transpose, coalesced both sides)
__global__ __launch_bounds__(256) void pack_wu(const float* __restrict__ W,
                                               const float* __restrict__ U,
                                               float* __restrict__ out,
                                               int DIN, int H) {
  __shared__ float tile[64][65];
  const int KT = DIN + H;
  const int c0 = blockIdx.x * 64;
  const int k0 = blockIdx.y * 64;
  const int tx = threadIdx.x & 63;
  const int ty = threadIdx.x >> 6;
  for (int r = ty; r < 64; r += 4) {
    const int k = k0 + r;
    tile[r][tx] = (k < DIN) ? W[(size_t)k * (4 * H) + c0 + tx]
                            : U[(size_t)(k - DIN) * (4 * H) + c0 + tx];
  }
  __syncthreads();
  for (int r = ty; r < 64; r += 4) {
    out[(size_t)(c0 + r) * KT + k0 + tx] = tile[tx][r];
  }
}

// One LSTM layer. Grid = NWG workgroups of 256 threads (4 waves).
// lane = batch. WG owns NH hidden units (x4 gates = C cols). Waves split K.
// Per-step grid barrier via monotonic counters in bar[t].
template <int DIN, int H, int NWG, int NH, bool FIN>
__global__ __launch_bounds__(256) void lstm_layer(
    const float* __restrict__ xin,   // [T][DIN/4][64][4]
    float* __restrict__ hseq,        // [T][H/4][64][4]
    const float* __restrict__ wuT,   // [4H][DIN+H]
    const float* __restrict__ bias,  // [4H]
    float* __restrict__ dout,        // [64][H] or null
    unsigned int* __restrict__ bar)  // [T]
{
  constexpr int C = 4 * NH;
  constexpr int KT = DIN + H;
  constexpr int NQ1 = DIN / 4;
  constexpr int NQ2 = H / 4;
  constexpr int T = 256;

  __shared__ float sZ[4][C][64];

  const int tid = threadIdx.x;
  const int lane = tid & 63;
  const int wv = tid >> 6;
  const int wg = blockIdx.x;

  const float* wrow[C];
#pragma unroll
  for (int c = 0; c < C; ++c) {
    const int cg = (c / NH) * H + wg * NH + (c % NH);
    wrow[c] = wuT + (size_t)cg * KT;
  }

  const bool ga = tid < 64 * NH;  // gate-stage threads: (jl = wv, b = lane)
  float bz0 = 0.f, bz1 = 0.f, bz2 = 0.f, bz3 = 0.f, cst = 0.f;
  if (ga) {
    const int j = wg * NH + wv;
    bz0 = bias[0 * H + j];
    bz1 = bias[1 * H + j];
    bz2 = bias[2 * H + j];
    bz3 = bias[3 * H + j];
  }

  const int q1a = wv * (NQ1 / 4), q1n = NQ1 / 4;
  const int q2a = wv * (NQ2 / 4), q2n = NQ2 / 4;

  for (int t = 0; t < T; ++t) {
    float acc[C];
#pragma unroll
    for (int c = 0; c < C; ++c) acc[c] = 0.f;

    // ---- input projection part (independent of barrier; overlaps waiting) ----
    const float* xt = xin + (size_t)t * NQ1 * 256;
#pragma unroll 4
    for (int qi = 0; qi < q1n; ++qi) {
      const int q = q1a + qi;
      const float4 xv = *(const float4*)(xt + (size_t)q * 256 + lane * 4);
#pragma unroll
      for (int c = 0; c < C; ++c) {
        const float4 w4 = *(const float4*)(wrow[c] + 4 * q);
        acc[c] = fmaf(w4.x, xv.x, acc[c]);
        acc[c] = fmaf(w4.y, xv.y, acc[c]);
        acc[c] = fmaf(w4.z, xv.z, acc[c]);
        acc[c] = fmaf(w4.w, xv.w, acc[c]);
      }
    }

    // ---- recurrent part ----
    if (t > 0) {
      if (tid == 0) {
        while (__hip_atomic_load(&bar[t - 1], __ATOMIC_RELAXED, AGENT) <
               (unsigned)NWG) {
        }
      }
      __syncthreads();
      const float* hp = hseq + (size_t)(t - 1) * NQ2 * 256;
#pragma unroll 4
      for (int qi = 0; qi < q2n; ++qi) {
        const int q = q2a + qi;
        unsigned long long* p =
            (unsigned long long*)(hp + (size_t)q * 256 + lane * 4);
        const unsigned long long d0 =
            __hip_atomic_load(p, __ATOMIC_RELAXED, AGENT);
        const unsigned long long d1 =
            __hip_atomic_load(p + 1, __ATOMIC_RELAXED, AGENT);
        float4 hv;
        hv.x = __uint_as_float((unsigned)d0);
        hv.y = __uint_as_float((unsigned)(d0 >> 32));
        hv.z = __uint_as_float((unsigned)d1);
        hv.w = __uint_as_float((unsigned)(d1 >> 32));
#pragma unroll
        for (int c = 0; c < C; ++c) {
          const float4 w4 = *(const float4*)(wrow[c] + DIN + 4 * q);
          acc[c] = fmaf(w4.x, hv.x, acc[c]);
          acc[c] = fmaf(w4.y, hv.y, acc[c]);
          acc[c] = fmaf(w4.z, hv.z, acc[c]);
          acc[c] = fmaf(w4.w, hv.w, acc[c]);
        }
      }
    }

    // ---- K-split reduction + gates ----
#pragma unroll
    for (int c = 0; c < C; ++c) sZ[wv][c][lane] = acc[c];
    __syncthreads();

    if (ga) {
      const int b = lane, jl = wv;
      const int j = wg * NH + jl;
      float z0 = bz0 + sZ[0][0 * NH + jl][b] + sZ[1][0 * NH + jl][b] +
                 sZ[2][0 * NH + jl][b] + sZ[3][0 * NH + jl][b];
      float z1 = bz1 + sZ[0][1 * NH + jl][b] + sZ[1][1 * NH + jl][b] +
                 sZ[2][1 * NH + jl][b] + sZ[3][1 * NH + jl][b];
      float z2 = bz2 + sZ[0][2 * NH + jl][b] + sZ[1][2 * NH + jl][b] +
                 sZ[2][2 * NH + jl][b] + sZ[3][2 * NH + jl][b];
      float z3 = bz3 + sZ[0][3 * NH + jl][b] + sZ[1][3 * NH + jl][b] +
                 sZ[2][3 * NH + jl][b] + sZ[3][3 * NH + jl][b];
      const float ig = 1.f / (1.f + expf(-z0));
      const float fg = 1.f / (1.f + expf(-z1));
      const float gg = FIN ? tanhf(z2) : fmaxf(z2, 0.f);
      const float og = 1.f / (1.f + expf(-z3));
      cst = fg * cst + ig * gg;
      const float ca = FIN ? tanhf(cst) : fmaxf(cst, 0.f);
      const float h = og * ca;
      float* hw = hseq + (size_t)t * NQ2 * 256;
      __hip_atomic_store(&hw[(size_t)(j >> 2) * 256 + (size_t)b * 4 + (j & 3)],
                         h, __ATOMIC_RELAXED, AGENT);
      if (FIN && t == T - 1) dout[(size_t)b * H + j] = h;
    }

    // drain h stores to device scope, then signal this step
    asm volatile("s_waitcnt vmcnt(0)" ::: "memory");
    __syncthreads();
    if (tid == 0) __hip_atomic_fetch_add(&bar[t], 1u, __ATOMIC_RELAXED, AGENT);
  }
}

extern "C" void kernel_launch(void* const* d_in, const int* in_sizes, int n_in,
                              void* d_out, int out_size, void* d_ws,
                              size_t ws_size, hipStream_t stream) {
  (void)in_sizes; (void)n_in; (void)out_size; (void)ws_size;
  const float* x = (const float*)d_in[0];
  const float* W[6];
  const float* U[6];
  const float* B[6];
  for (int l = 0; l < 6; ++l) {
    W[l] = (const float*)d_in[1 + 3 * l];
    U[l] = (const float*)d_in[2 + 3 * l];
    B[l] = (const float*)d_in[3 + 3 * l];
  }
  char* ws = (char*)d_ws;
  unsigned int* bar = (unsigned int*)ws;  // 6*256 counters
  float* wuT0 = (float*)(ws + (1u << 20));
  float* wuT1 = wuT0 + (size_t)2048 * 768;
  float* wuT2 = wuT1 + (size_t)1024 * 768;
  float* wuT3 = wuT2 + (size_t)256 * 320;
  float* wuT4 = wuT3 + (size_t)1024 * 320;
  float* wuT5 = wuT4 + (size_t)2048 * 768;
  float* buf0 = (float*)(ws + (22u << 20));  // 16 MB region
  float* buf1 = (float*)(ws + (39u << 20));  // 32 MB region

  hipMemsetAsync(bar, 0, 6 * 256 * sizeof(unsigned), stream);
  xpose_in<<<256, 256, 0, stream>>>(x, buf0);
  pack_wu<<<dim3(32, 12), 256, 0, stream>>>(W[0], U[0], wuT0, 256, 512);
  pack_wu<<<dim3(16, 12), 256, 0, stream>>>(W[1], U[1], wuT1, 512, 256);
  pack_wu<<<dim3(4, 5), 256, 0, stream>>>(W[2], U[2], wuT2, 256, 64);
  pack_wu<<<dim3(16, 5), 256, 0, stream>>>(W[3], U[3], wuT3, 64, 256);
  pack_wu<<<dim3(32, 12), 256, 0, stream>>>(W[4], U[4], wuT4, 256, 512);
  pack_wu<<<dim3(16, 12), 256, 0, stream>>>(W[5], U[5], wuT5, 512, 256);

  lstm_layer<256, 512, 256, 2, false>
      <<<256, 256, 0, stream>>>(buf0, buf1, wuT0, B[0], nullptr, bar + 0);
  lstm_layer<512, 256, 128, 2, false>
      <<<128, 256, 0, stream>>>(buf1, buf0, wuT1, B[1], nullptr, bar + 256);
  lstm_layer<256, 64, 64, 1, false>
      <<<64, 256, 0, stream>>>(buf0, buf1, wuT2, B[2], nullptr, bar + 512);
  lstm_layer<64, 256, 128, 2, false>
      <<<128, 256, 0, stream>>>(buf1, buf0, wuT3, B[3], nullptr, bar + 768);
  lstm_layer<256, 512, 256, 2, false>
      <<<256, 256, 0, stream>>>(buf0, buf1, wuT4, B[4], nullptr, bar + 1024);
  lstm_layer<512, 256, 128, 2, true>
      <<<128, 256, 0, stream>>>(buf1, buf0, wuT5, B[5], (float*)d_out,
                                bar + 1280);
}

// Round 2
// 23546.404 us; speedup vs baseline: 1.0174x; 1.0174x over previous
//
#include <hip/hip_runtime.h>
#include <stdint.h>

#define AGENT __HIP_MEMORY_SCOPE_AGENT

// x[64][256][256] -> xT[t][iq][b][4]   (packed quads of input dim, batch-minor)
__global__ __launch_bounds__(256) void xpose_in(const float* __restrict__ x,
                                                float* __restrict__ xT) {
  const int t = blockIdx.x;
  const int b = threadIdx.x & 63;
  const int w = threadIdx.x >> 6;
  const float* xr = x + ((size_t)b * 256 + t) * 256;
  float* o = xT + (size_t)t * 64 * 256;
  for (int iq = w * 16; iq < w * 16 + 16; ++iq) {
    float4 v = *(const float4*)(xr + iq * 4);
    *(float4*)(o + ((size_t)iq * 64 + b) * 4) = v;
  }
}

// Pack [W;U] ([KT][4H], col cg) into wuT[cg][k] (transpose, coalesced both sides)
__global__ __launch_bounds__(256) void pack_wu(const float* __restrict__ W,
                                               const float* __restrict__ U,
                                               float* __restrict__ out,
                                               int DIN, int H) {
  __shared__ float tile[64][65];
  const int KT = DIN + H;
  const int c0 = blockIdx.x * 64;
  const int k0 = blockIdx.y * 64;
  const int tx = threadIdx.x & 63;
  const int ty = threadIdx.x >> 6;
  for (int r = ty; r < 64; r += 4) {
    const int k = k0 + r;
    tile[r][tx] = (k < DIN) ? W[(size_t)k * (4 * H) + c0 + tx]
                            : U[(size_t)(k - DIN) * (4 * H) + c0 + tx];
  }
  __syncthreads();
  for (int r = ty; r < 64; r += 4) {
    out[(size_t)(c0 + r) * KT + k0 + tx] = tile[tx][r];
  }
}

// One LSTM layer. Grid = NWG workgroups of 256 threads (4 waves).
// lane = batch. WG owns NH hidden units (x4 gates = C cols). Waves split K.
// Per-step sync: producer WG w stores flg[t*NWG+w]=1 (distinct addresses, no
// RMW serialization); consumers poll all NWG flags (coalesced spin loads).
template <int DIN, int H, int NWG, int NH, bool FIN>
__global__ __launch_bounds__(256) void lstm_layer(
    const float* __restrict__ xin,   // [T][DIN/4][64][4]
    float* __restrict__ hseq,        // [T][H/4][64][4]
    const float* __restrict__ wuT,   // [4H][DIN+H]
    const float* __restrict__ bias,  // [4H]
    float* __restrict__ dout,        // [64][H] or null
    unsigned int* __restrict__ flg)  // [T][NWG]
{
  constexpr int C = 4 * NH;
  constexpr int KT = DIN + H;
  constexpr int NQ1 = DIN / 4;
  constexpr int NQ2 = H / 4;
  constexpr int T = 256;

  __shared__ float sZ[4][C][64];

  const int tid = threadIdx.x;
  const int lane = tid & 63;
  const int wv = tid >> 6;
  const int wg = blockIdx.x;

  const float* wrow[C];
#pragma unroll
  for (int c = 0; c < C; ++c) {
    const int cg = (c / NH) * H + wg * NH + (c % NH);
    wrow[c] = wuT + (size_t)cg * KT;
  }

  const bool ga = tid < 64 * NH;  // gate-stage threads: (jl = wv, b = lane)
  float bz0 = 0.f, bz1 = 0.f, bz2 = 0.f, bz3 = 0.f, cst = 0.f;
  if (ga) {
    const int j = wg * NH + wv;
    bz0 = bias[0 * H + j];
    bz1 = bias[1 * H + j];
    bz2 = bias[2 * H + j];
    bz3 = bias[3 * H + j];
  }

  const int q1a = wv * (NQ1 / 4), q1n = NQ1 / 4;
  const int q2a = wv * (NQ2 / 4), q2n = NQ2 / 4;

  for (int t = 0; t < T; ++t) {
    float acc[C];
#pragma unroll
    for (int c = 0; c < C; ++c) acc[c] = 0.f;

    // ---- input projection part (independent of sync; overlaps waiting) ----
    const float* xt = xin + (size_t)t * NQ1 * 256;
#pragma unroll 4
    for (int qi = 0; qi < q1n; ++qi) {
      const int q = q1a + qi;
      const float4 xv = *(const float4*)(xt + (size_t)q * 256 + lane * 4);
#pragma unroll
      for (int c = 0; c < C; ++c) {
        const float4 w4 = *(const float4*)(wrow[c] + 4 * q);
        acc[c] = fmaf(w4.x, xv.x, acc[c]);
        acc[c] = fmaf(w4.y, xv.y, acc[c]);
        acc[c] = fmaf(w4.z, xv.z, acc[c]);
        acc[c] = fmaf(w4.w, xv.w, acc[c]);
      }
    }

    // ---- recurrent part ----
    if (t > 0) {
      if (tid < NWG) {
        while (__hip_atomic_load(&flg[(t - 1) * NWG + tid], __ATOMIC_RELAXED,
                                 AGENT) == 0u) {
        }
      }
      __syncthreads();
      const float* hp = hseq + (size_t)(t - 1) * NQ2 * 256;
#pragma unroll 4
      for (int qi = 0; qi < q2n; ++qi) {
        const int q = q2a + qi;
        unsigned long long* p =
            (unsigned long long*)(hp + (size_t)q * 256 + lane * 4);
        const unsigned long long d0 =
            __hip_atomic_load(p, __ATOMIC_RELAXED, AGENT);
        const unsigned long long d1 =
            __hip_atomic_load(p + 1, __ATOMIC_RELAXED, AGENT);
        float4 hv;
        hv.x = __uint_as_float((unsigned)d0);
        hv.y = __uint_as_float((unsigned)(d0 >> 32));
        hv.z = __uint_as_float((unsigned)d1);
        hv.w = __uint_as_float((unsigned)(d1 >> 32));
#pragma unroll
        for (int c = 0; c < C; ++c) {
          const float4 w4 = *(const float4*)(wrow[c] + DIN + 4 * q);
          acc[c] = fmaf(w4.x, hv.x, acc[c]);
          acc[c] = fmaf(w4.y, hv.y, acc[c]);
          acc[c] = fmaf(w4.z, hv.z, acc[c]);
          acc[c] = fmaf(w4.w, hv.w, acc[c]);
        }
      }
    }

    // ---- K-split reduction + gates ----
#pragma unroll
    for (int c = 0; c < C; ++c) sZ[wv][c][lane] = acc[c];
    __syncthreads();

    if (ga) {
      const int b = lane, jl = wv;
      const int j = wg * NH + jl;
      float z0 = bz0 + sZ[0][0 * NH + jl][b] + sZ[1][0 * NH + jl][b] +
                 sZ[2][0 * NH + jl][b] + sZ[3][0 * NH + jl][b];
      float z1 = bz1 + sZ[0][1 * NH + jl][b] + sZ[1][1 * NH + jl][b] +
                 sZ[2][1 * NH + jl][b] + sZ[3][1 * NH + jl][b];
      float z2 = bz2 + sZ[0][2 * NH + jl][b] + sZ[1][2 * NH + jl][b] +
                 sZ[2][2 * NH + jl][b] + sZ[3][2 * NH + jl][b];
      float z3 = bz3 + sZ[0][3 * NH + jl][b] + sZ[1][3 * NH + jl][b] +
                 sZ[2][3 * NH + jl][b] + sZ[3][3 * NH + jl][b];
      const float ig = 1.f / (1.f + expf(-z0));
      const float fg = 1.f / (1.f + expf(-z1));
      const float gg = FIN ? tanhf(z2) : fmaxf(z2, 0.f);
      const float og = 1.f / (1.f + expf(-z3));
      cst = fg * cst + ig * gg;
      const float ca = FIN ? tanhf(cst) : fmaxf(cst, 0.f);
      const float h = og * ca;
      float* hw = hseq + (size_t)t * NQ2 * 256;
      __hip_atomic_store(&hw[(size_t)(j >> 2) * 256 + (size_t)b * 4 + (j & 3)],
                         h, __ATOMIC_RELAXED, AGENT);
      if (FIN && t == T - 1) dout[(size_t)b * H + j] = h;
    }

    // drain h stores to device scope, then signal this step (per-WG flag)
    asm volatile("s_waitcnt vmcnt(0)" ::: "memory");
    __syncthreads();
    if (tid == 0)
      __hip_atomic_store(&flg[t * NWG + wg], 1u, __ATOMIC_RELAXED, AGENT);
  }
}

extern "C" void kernel_launch(void* const* d_in, const int* in_sizes, int n_in,
                              void* d_out, int out_size, void* d_ws,
                              size_t ws_size, hipStream_t stream) {
  (void)in_sizes; (void)n_in; (void)out_size; (void)ws_size;
  const float* x = (const float*)d_in[0];
  const float* W[6];
  const float* U[6];
  const float* B[6];
  for (int l = 0; l < 6; ++l) {
    W[l] = (const float*)d_in[1 + 3 * l];
    U[l] = (const float*)d_in[2 + 3 * l];
    B[l] = (const float*)d_in[3 + 3 * l];
  }
  char* ws = (char*)d_ws;
  // flags: per-layer [T][NWG] packed; NWG = 256,128,64,128,256,128 -> 983040 B
  unsigned int* flg = (unsigned int*)ws;
  unsigned int* f0 = flg;
  unsigned int* f1 = f0 + 256 * 256;
  unsigned int* f2 = f1 + 256 * 128;
  unsigned int* f3 = f2 + 256 * 64;
  unsigned int* f4 = f3 + 256 * 128;
  unsigned int* f5 = f4 + 256 * 256;
  float* wuT0 = (float*)(ws + (1u << 20));
  float* wuT1 = wuT0 + (size_t)2048 * 768;
  float* wuT2 = wuT1 + (size_t)1024 * 768;
  float* wuT3 = wuT2 + (size_t)256 * 320;
  float* wuT4 = wuT3 + (size_t)1024 * 320;
  float* wuT5 = wuT4 + (size_t)2048 * 768;
  float* buf0 = (float*)(ws + (22u << 20));  // 16 MB region
  float* buf1 = (float*)(ws + (39u << 20));  // 32 MB region

  hipMemsetAsync(flg, 0, 256 * 960 * sizeof(unsigned), stream);
  xpose_in<<<256, 256, 0, stream>>>(x, buf0);
  pack_wu<<<dim3(32, 12), 256, 0, stream>>>(W[0], U[0], wuT0, 256, 512);
  pack_wu<<<dim3(16, 12), 256, 0, stream>>>(W[1], U[1], wuT1, 512, 256);
  pack_wu<<<dim3(4, 5), 256, 0, stream>>>(W[2], U[2], wuT2, 256, 64);
  pack_wu<<<dim3(16, 5), 256, 0, stream>>>(W[3], U[3], wuT3, 64, 256);
  pack_wu<<<dim3(32, 12), 256, 0, stream>>>(W[4], U[4], wuT4, 256, 512);
  pack_wu<<<dim3(16, 12), 256, 0, stream>>>(W[5], U[5], wuT5, 512, 256);

  lstm_layer<256, 512, 256, 2, false>
      <<<256, 256, 0, stream>>>(buf0, buf1, wuT0, B[0], nullptr, f0);
  lstm_layer<512, 256, 128, 2, false>
      <<<128, 256, 0, stream>>>(buf1, buf0, wuT1, B[1], nullptr, f1);
  lstm_layer<256, 64, 64, 1, false>
      <<<64, 256, 0, stream>>>(buf0, buf1, wuT2, B[2], nullptr, f2);
  lstm_layer<64, 256, 128, 2, false>
      <<<128, 256, 0, stream>>>(buf1, buf0, wuT3, B[3], nullptr, f3);
  lstm_layer<256, 512, 256, 2, false>
      <<<256, 256, 0, stream>>>(buf0, buf1, wuT4, B[4], nullptr, f4);
  lstm_layer<512, 256, 128, 2, true>
      <<<128, 256, 0, stream>>>(buf1, buf0, wuT5, B[5], (float*)d_out, f5);
}

// Round 3
// 21313.979 us; speedup vs baseline: 1.1239x; 1.1047x over previous
//
#include <hip/hip_runtime.h>
#include <stdint.h>

#define AGENT __HIP_MEMORY_SCOPE_AGENT
typedef unsigned long long u64;

// x[64][256][256] -> xT[t][iq][b][4]   (packed quads of input dim, batch-minor)
__global__ __launch_bounds__(256) void xpose_in(const float* __restrict__ x,
                                                float* __restrict__ xT) {
  const int t = blockIdx.x;
  const int b = threadIdx.x & 63;
  const int w = threadIdx.x >> 6;
  const float* xr = x + ((size_t)b * 256 + t) * 256;
  float* o = xT + (size_t)t * 64 * 256;
  for (int iq = w * 16; iq < w * 16 + 16; ++iq) {
    float4 v = *(const float4*)(xr + iq * 4);
    *(float4*)(o + ((size_t)iq * 64 + b) * 4) = v;
  }
}

// Pack [W;U] ([KT][4H], col cg) into wuT[cg][k] (transpose, coalesced both sides)
__global__ __launch_bounds__(256) void pack_wu(const float* __restrict__ W,
                                               const float* __restrict__ U,
                                               float* __restrict__ out,
                                               int DIN, int H) {
  __shared__ float tile[64][65];
  const int KT = DIN + H;
  const int c0 = blockIdx.x * 64;
  const int k0 = blockIdx.y * 64;
  const int tx = threadIdx.x & 63;
  const int ty = threadIdx.x >> 6;
  for (int r = ty; r < 64; r += 4) {
    const int k = k0 + r;
    tile[r][tx] = (k < DIN) ? W[(size_t)k * (4 * H) + c0 + tx]
                            : U[(size_t)(k - DIN) * (4 * H) + c0 + tx];
  }
  __syncthreads();
  for (int r = ty; r < 64; r += 4) {
    out[(size_t)(c0 + r) * KT + k0 + tx] = tile[tx][r];
  }
}

template <bool COH>
__device__ __forceinline__ float4 ld16(const float* p) {
  if (COH) {
    u64 a = __hip_atomic_load((u64*)p, __ATOMIC_RELAXED, AGENT);
    u64 b = __hip_atomic_load((u64*)p + 1, __ATOMIC_RELAXED, AGENT);
    float4 v;
    v.x = __uint_as_float((unsigned)a);
    v.y = __uint_as_float((unsigned)(a >> 32));
    v.z = __uint_as_float((unsigned)b);
    v.w = __uint_as_float((unsigned)(b >> 32));
    return v;
  } else {
    return *(const float4*)p;
  }
}

// Accumulate QW quads (this wave's K-slice) of src into acc[16].
// src layout: [quad][64][4]; weights: 4 gate-base rows, jl*KT apart.
// Double-buffered in chunks of 4 quads so coherent-load latency pipelines.
template <bool COH, int QW, int KT>
__device__ __forceinline__ void accum(const float* __restrict__ src, int q0,
                                      int kof0, const float* const bg[4],
                                      int lane, float acc[16]) {
  constexpr int NCH = QW / 4;
  float4 cur[4], nxt[4];
#pragma unroll
  for (int i = 0; i < 4; ++i)
    cur[i] = ld16<COH>(src + (size_t)(q0 + i) * 256 + lane * 4);
  for (int ch = 0; ch < NCH; ++ch) {
    const int qb = q0 + ch * 4;
    if (ch + 1 < NCH) {
#pragma unroll
      for (int i = 0; i < 4; ++i)
        nxt[i] = ld16<COH>(src + (size_t)(qb + 4 + i) * 256 + lane * 4);
    }
#pragma unroll
    for (int i = 0; i < 4; ++i) {
      const int kof = kof0 + 4 * (qb + i);
      const float4 xv = cur[i];
#pragma unroll
      for (int g = 0; g < 4; ++g) {
#pragma unroll
        for (int jl = 0; jl < 4; ++jl) {
          const float4 w = *(const float4*)(bg[g] + (size_t)jl * KT + kof);
          float& a = acc[g * 4 + jl];
          a = fmaf(w.x, xv.x, a);
          a = fmaf(w.y, xv.y, a);
          a = fmaf(w.z, xv.z, a);
          a = fmaf(w.w, xv.w, a);
        }
      }
    }
#pragma unroll
    for (int i = 0; i < 4; ++i) cur[i] = nxt[i];
  }
}

// One pipelined LSTM layer. WG owns hidden quad q=wg (NH=4 units, C=16 cols).
// lane = batch, wave = unit-within-quad for gates / K-slice for fma.
// Sync: selfF[t][wg] (recurrence, t-1), prevF[t][wg'] (input from layer l-1).
template <int DIN, int H, int NWG, int NWGP, bool FIN, bool RING, bool XCOH>
__device__ __forceinline__ void layer_body(
    int wg, int tid, const float* __restrict__ xin, float* __restrict__ hseq,
    const float* __restrict__ wuT, const float* __restrict__ bias,
    float* __restrict__ dout, unsigned* __restrict__ selfF,
    unsigned* __restrict__ prevF, float (*sZ)[16][64], float* sH) {
  constexpr int NQ1 = DIN / 4;
  constexpr int NQ2 = H / 4;
  constexpr int KT = DIN + H;
  constexpr int QW1 = NQ1 / 4;
  constexpr int QW2 = NQ2 / 4;
  constexpr int T = 256;

  const int lane = tid & 63;
  const int wv = tid >> 6;

  const float* bg[4];
#pragma unroll
  for (int g = 0; g < 4; ++g) bg[g] = wuT + ((size_t)g * H + wg * 4) * KT;

  float bz[4];
#pragma unroll
  for (int g = 0; g < 4; ++g) bz[g] = bias[g * H + wg * 4 + wv];

  float cst = 0.f;

  for (int t = 0; t < T; ++t) {
    float acc[16];
#pragma unroll
    for (int c = 0; c < 16; ++c) acc[c] = 0.f;

    if (!XCOH) {
      // layer 0: x is static — compute input projection while peers finish
      accum<false, QW1, KT>(xin + (size_t)t * NQ1 * 256, wv * QW1, 0, bg, lane,
                            acc);
    }
    // wait for recurrence (self, t-1) and input (prev layer, t)
    if (t > 0 && tid < NWG) {
      while (__hip_atomic_load(&selfF[(t - 1) * NWG + tid], __ATOMIC_RELAXED,
                               AGENT) == 0u) {
      }
    }
    if (XCOH) {
      if (tid >= 128 && tid < 128 + NWGP) {
        while (__hip_atomic_load(&prevF[t * NWGP + (tid - 128)],
                                 __ATOMIC_RELAXED, AGENT) == 0u) {
        }
      }
    }
    __syncthreads();

    if (XCOH) {
      accum<true, QW1, KT>(xin + (size_t)t * NQ1 * 256, wv * QW1, 0, bg, lane,
                           acc);
    }
    if (t > 0) {
      const float* hp =
          hseq + (size_t)(RING ? ((t - 1) & 1) : (t - 1)) * NQ2 * 256;
      accum<true, QW2, KT>(hp, wv * QW2, DIN, bg, lane, acc);
    }

    // K-split reduction across the 4 waves
#pragma unroll
    for (int c = 0; c < 16; ++c) sZ[wv][c][lane] = acc[c];
    __syncthreads();

    float z[4];
#pragma unroll
    for (int g = 0; g < 4; ++g) {
      z[g] = bz[g];
#pragma unroll
      for (int k = 0; k < 4; ++k) z[g] += sZ[k][g * 4 + wv][lane];
    }
    const float ig = 1.f / (1.f + __expf(-z[0]));
    const float fg = 1.f / (1.f + __expf(-z[1]));
    const float gg = FIN ? tanhf(z[2]) : fmaxf(z[2], 0.f);
    const float og = 1.f / (1.f + __expf(-z[3]));
    cst = fg * cst + ig * gg;
    const float ca = FIN ? tanhf(cst) : fmaxf(cst, 0.f);
    const float h = og * ca;
    sH[lane * 4 + wv] = h;  // [b][jl]
    if (FIN && t == T - 1) dout[(size_t)lane * H + wg * 4 + wv] = h;
    __syncthreads();

    // wave 0 publishes the WG's 1 KB h-block coalesced, then signals
    if (wv == 0) {
      const float4 v = *(const float4*)&sH[lane * 4];
      float* hw = hseq + (size_t)(RING ? (t & 1) : t) * NQ2 * 256 +
                  (size_t)wg * 256 + lane * 4;
      const u64 lo = ((u64)__float_as_uint(v.y) << 32) | __float_as_uint(v.x);
      const u64 hi = ((u64)__float_as_uint(v.w) << 32) | __float_as_uint(v.z);
      __hip_atomic_store((u64*)hw, lo, __ATOMIC_RELAXED, AGENT);
      __hip_atomic_store((u64*)hw + 1, hi, __ATOMIC_RELAXED, AGENT);
      asm volatile("s_waitcnt vmcnt(0)" ::: "memory");
      if (tid == 0)
        __hip_atomic_store(&selfF[t * NWG + wg], 1u, __ATOMIC_RELAXED, AGENT);
    }
  }
}

__global__ __launch_bounds__(256, 2) void lstm_fused(
    const float* __restrict__ xT, float* __restrict__ h0,
    float* __restrict__ h1, float* __restrict__ h2, float* __restrict__ h3,
    float* __restrict__ h4, float* __restrict__ h5,
    const float* __restrict__ wuT0, const float* __restrict__ wuT1,
    const float* __restrict__ wuT2, const float* __restrict__ wuT3,
    const float* __restrict__ wuT4, const float* __restrict__ wuT5,
    const float* __restrict__ b0, const float* __restrict__ b1,
    const float* __restrict__ b2, const float* __restrict__ b3,
    const float* __restrict__ b4, const float* __restrict__ b5,
    float* __restrict__ dout, unsigned* __restrict__ f0,
    unsigned* __restrict__ f1, unsigned* __restrict__ f2,
    unsigned* __restrict__ f3, unsigned* __restrict__ f4,
    unsigned* __restrict__ f5) {
  __shared__ float sZ[4][16][64];
  __shared__ float sH[256];
  const int b = blockIdx.x;
  const int tid = threadIdx.x;
  // heavy layers first so they land one-per-CU
  if (b < 128) {
    layer_body<256, 512, 128, 0, false, false, false>(b, tid, xT, h0, wuT0, b0,
                                                      nullptr, f0, nullptr, sZ,
                                                      sH);
  } else if (b < 256) {
    layer_body<256, 512, 128, 64, false, false, true>(b - 128, tid, h3, h4,
                                                      wuT4, b4, nullptr, f4, f3,
                                                      sZ, sH);
  } else if (b < 320) {
    layer_body<512, 256, 64, 128, false, false, true>(b - 256, tid, h0, h1,
                                                      wuT1, b1, nullptr, f1, f0,
                                                      sZ, sH);
  } else if (b < 384) {
    layer_body<64, 256, 64, 16, false, false, true>(b - 320, tid, h2, h3, wuT3,
                                                    b3, nullptr, f3, f2, sZ,
                                                    sH);
  } else if (b < 448) {
    layer_body<512, 256, 64, 128, true, true, true>(b - 384, tid, h4, h5, wuT5,
                                                    b5, dout, f5, f4, sZ, sH);
  } else {
    layer_body<256, 64, 16, 64, false, false, true>(b - 448, tid, h1, h2, wuT2,
                                                    b2, nullptr, f2, f1, sZ,
                                                    sH);
  }
}

extern "C" void kernel_launch(void* const* d_in, const int* in_sizes, int n_in,
                              void* d_out, int out_size, void* d_ws,
                              size_t ws_size, hipStream_t stream) {
  (void)in_sizes; (void)n_in; (void)out_size; (void)ws_size;
  const float* x = (const float*)d_in[0];
  const float* W[6];
  const float* U[6];
  const float* B[6];
  for (int l = 0; l < 6; ++l) {
    W[l] = (const float*)d_in[1 + 3 * l];
    U[l] = (const float*)d_in[2 + 3 * l];
    B[l] = (const float*)d_in[3 + 3 * l];
  }
  char* ws = (char*)d_ws;
  // flags: [T][NWG] per layer; NWG = 128,64,16,64,128,64
  unsigned* f0 = (unsigned*)ws;
  unsigned* f1 = f0 + 128 * 256;
  unsigned* f2 = f1 + 64 * 256;
  unsigned* f3 = f2 + 16 * 256;
  unsigned* f4 = f3 + 64 * 256;
  unsigned* f5 = f4 + 128 * 256;
  float* wuT0 = (float*)(ws + (1u << 20));
  float* wuT1 = wuT0 + (size_t)2048 * 768;
  float* wuT2 = wuT1 + (size_t)1024 * 768;
  float* wuT3 = wuT2 + (size_t)256 * 320;
  float* wuT4 = wuT3 + (size_t)1024 * 320;
  float* wuT5 = wuT4 + (size_t)2048 * 768;
  float* xT = (float*)(ws + (22u << 20));   // 16 MB
  float* h0 = (float*)(ws + (38u << 20));   // 32 MB
  float* h1 = (float*)(ws + (70u << 20));   // 16 MB
  float* h2 = (float*)(ws + (86u << 20));   // 4 MB
  float* h3 = (float*)(ws + (90u << 20));   // 16 MB
  float* h4 = (float*)(ws + (106u << 20));  // 32 MB
  float* h5 = (float*)(ws + (138u << 20));  // 128 KB ring (depth 2)

  hipMemsetAsync(f0, 0, 464 * 256 * sizeof(unsigned), stream);
  xpose_in<<<256, 256, 0, stream>>>(x, xT);
  pack_wu<<<dim3(32, 12), 256, 0, stream>>>(W[0], U[0], wuT0, 256, 512);
  pack_wu<<<dim3(16, 12), 256, 0, stream>>>(W[1], U[1], wuT1, 512, 256);
  pack_wu<<<dim3(4, 5), 256, 0, stream>>>(W[2], U[2], wuT2, 256, 64);
  pack_wu<<<dim3(16, 5), 256, 0, stream>>>(W[3], U[3], wuT3, 64, 256);
  pack_wu<<<dim3(32, 12), 256, 0, stream>>>(W[4], U[4], wuT4, 256, 512);
  pack_wu<<<dim3(16, 12), 256, 0, stream>>>(W[5], U[5], wuT5, 512, 256);

  lstm_fused<<<464, 256, 0, stream>>>(xT, h0, h1, h2, h3, h4, h5, wuT0, wuT1,
                                      wuT2, wuT3, wuT4, wuT5, B[0], B[1], B[2],
                                      B[3], B[4], B[5], (float*)d_out, f0, f1,
                                      f2, f3, f4, f5);
}